// Round 6
// baseline (430.274 us; speedup 1.0000x reference)
//
#include <hip/hip_runtime.h>
#include <math.h>

#define N_ENT  50000
#define N_REL  500
#define N_EDGE 800000
#define D      100
#define D2     50          // float2 lanes per row
#define ALPHA  0.2f

#define SCAN_B 256
#define NBLK_SCAN ((N_ENT + SCAN_B - 1) / SCAN_B)   // 196

// ---------------------------------------------------------------------------
// K1: Y = X @ W. 256 threads: tid<200 active; thread = (col, row-half),
// 8 rows/thread, 8 independent FMA chains. FULL k-unroll (25 compile-time
// tiles) so the compiler batches the 200 independent float4 loads with
// staggered vmcnt instead of one vmcnt(0) stall per tile.
// GUARD=false for the entity launch (50000 = 3125 blocks * 16 rows exact).
// ---------------------------------------------------------------------------
#define PROJ_RPT 8
template<bool GUARD>
__global__ __launch_bounds__(256) void proj_kernel(const float* __restrict__ X,
                                                   const float* __restrict__ W,
                                                   float* __restrict__ Y, int N) {
    int tid = threadIdx.x;
    if (tid >= 200) return;
    int half = tid / 100;
    int c    = tid % 100;
    int rbase = blockIdx.x * (2 * PROJ_RPT) + half * PROJ_RPT;

    float acc[PROJ_RPT];
    #pragma unroll
    for (int r = 0; r < PROJ_RPT; ++r) acc[r] = 0.f;

    #pragma unroll
    for (int k0 = 0; k0 < D; k0 += 4) {
        float4 xv[PROJ_RPT];
        #pragma unroll
        for (int r = 0; r < PROJ_RPT; ++r) {
            int row = rbase + r;
            if (GUARD)
                xv[r] = (row < N) ? *(const float4*)(X + (size_t)row * D + k0)
                                  : make_float4(0.f, 0.f, 0.f, 0.f);
            else
                xv[r] = *(const float4*)(X + (size_t)row * D + k0);
        }
        #pragma unroll
        for (int kk = 0; kk < 4; ++kk) {
            float w = W[(k0 + kk) * D + c];
            #pragma unroll
            for (int r = 0; r < PROJ_RPT; ++r) {
                float x = (kk == 0) ? xv[r].x : (kk == 1) ? xv[r].y
                        : (kk == 2) ? xv[r].z : xv[r].w;
                acc[r] = fmaf(x, w, acc[r]);
            }
        }
    }
    #pragma unroll
    for (int r = 0; r < PROJ_RPT; ++r) {
        int row = rbase + r;
        if (!GUARD || row < N) Y[(size_t)row * D + c] = acc[r];
    }
}

// ---------------------------------------------------------------------------
// CSR build: degree count -> block scan (3 kernels) -> fill buckets
// ---------------------------------------------------------------------------
__global__ void degree_kernel(const int* __restrict__ h_idx, int* __restrict__ deg) {
    int e = blockIdx.x * blockDim.x + threadIdx.x;
    if (e < N_EDGE) atomicAdd(&deg[h_idx[e]], 1);
}

__global__ void scan1_kernel(const int* __restrict__ deg, int* __restrict__ bsum) {
    __shared__ int s[SCAN_B];
    int i = blockIdx.x * SCAN_B + threadIdx.x;
    s[threadIdx.x] = (i < N_ENT) ? deg[i] : 0;
    __syncthreads();
    for (int off = SCAN_B / 2; off; off >>= 1) {
        if (threadIdx.x < off) s[threadIdx.x] += s[threadIdx.x + off];
        __syncthreads();
    }
    if (threadIdx.x == 0) bsum[blockIdx.x] = s[0];
}

__global__ void scan2_kernel(const int* __restrict__ bsum, int* __restrict__ boff) {
    __shared__ int s[SCAN_B];
    int tid = threadIdx.x;
    int v = (tid < NBLK_SCAN) ? bsum[tid] : 0;
    s[tid] = v;
    __syncthreads();
    for (int off = 1; off < SCAN_B; off <<= 1) {
        int x = (tid >= off) ? s[tid - off] : 0;
        __syncthreads();
        s[tid] += x;
        __syncthreads();
    }
    if (tid < NBLK_SCAN) boff[tid] = s[tid] - v;   // exclusive
}

__global__ void scan3_kernel(const int* __restrict__ deg, const int* __restrict__ boff,
                             int* __restrict__ rowptr, int* __restrict__ cursor) {
    __shared__ int s[SCAN_B];
    int tid = threadIdx.x;
    int i = blockIdx.x * SCAN_B + tid;
    int v = (i < N_ENT) ? deg[i] : 0;
    s[tid] = v;
    __syncthreads();
    for (int off = 1; off < SCAN_B; off <<= 1) {
        int x = (tid >= off) ? s[tid - off] : 0;
        __syncthreads();
        s[tid] += x;
        __syncthreads();
    }
    int excl = s[tid] - v + boff[blockIdx.x];
    if (i < N_ENT) { rowptr[i] = excl; cursor[i] = excl; }
    if (i == N_ENT - 1) rowptr[N_ENT] = excl + v;
}

__global__ void fill_kernel(const int* __restrict__ h_idx, const int* __restrict__ t_idx,
                            const int* __restrict__ etype, int* __restrict__ cursor,
                            int2* __restrict__ tr_sorted) {
    int e = blockIdx.x * blockDim.x + threadIdx.x;
    if (e >= N_EDGE) return;
    int h = h_idx[e];
    int pos = atomicAdd(&cursor[h], 1);
    tr_sorted[pos] = make_int2(t_idx[e], etype[e]);
}

// ---------------------------------------------------------------------------
// Fused per-head kernel: one 64-lane wave per head node, online softmax,
// unroll-by-2 so the two edges' gathers issue before either serial chain.
// ---------------------------------------------------------------------------
__device__ __forceinline__ float edge_reduce(float2 eh, float2 v) {
    float dx = eh.x + v.x, dy = eh.y + v.y;
    float s = fmaf(dx, dx, dy * dy);
    #pragma unroll
    for (int off = 32; off; off >>= 1) s += __shfl_xor(s, off, 64);
    return sqrtf(s);                       // leaky_relu identity (s >= 0)
}

__global__ void fused_kernel(const float* __restrict__ ent, const float* __restrict__ rel,
                             const int* __restrict__ rowptr,
                             const int2* __restrict__ tr_sorted,
                             float* __restrict__ out) {
    int head = blockIdx.x * 4 + (threadIdx.x >> 6);
    int lane = threadIdx.x & 63;
    if (head >= N_ENT) return;
    int beg = rowptr[head], end = rowptr[head + 1];

    float2 eh = make_float2(0.f, 0.f);
    if (lane < D2) eh = ((const float2*)(ent + (size_t)head * D))[lane];

    float  m   = -INFINITY;
    float  den = 0.f;
    float2 acc = make_float2(0.f, 0.f);

    int i = beg;
    for (; i + 1 < end; i += 2) {
        int2 e0 = tr_sorted[i];
        int2 e1 = tr_sorted[i + 1];
        float2 v0 = make_float2(0.f, 0.f), v1 = make_float2(0.f, 0.f);
        if (lane < D2) {
            float2 et0 = ((const float2*)(ent + (size_t)e0.x * D))[lane];
            float2 er0 = ((const float2*)(rel + (size_t)e0.y * D))[lane];
            float2 et1 = ((const float2*)(ent + (size_t)e1.x * D))[lane];
            float2 er1 = ((const float2*)(rel + (size_t)e1.y * D))[lane];
            v0 = make_float2(er0.x - et0.x, er0.y - et0.y);
            v1 = make_float2(er1.x - et1.x, er1.y - et1.y);
        }
        float sc0 = edge_reduce(eh, v0);
        float sc1 = edge_reduce(eh, v1);

        float mn    = fmaxf(m, sc0);
        float scale = __expf(m - mn);
        float ex    = __expf(sc0 - mn);
        den   = den * scale + ex;
        acc.x = acc.x * scale - v0.x * ex;
        acc.y = acc.y * scale - v0.y * ex;
        m = mn;

        mn    = fmaxf(m, sc1);
        scale = __expf(m - mn);
        ex    = __expf(sc1 - mn);
        den   = den * scale + ex;
        acc.x = acc.x * scale - v1.x * ex;
        acc.y = acc.y * scale - v1.y * ex;
        m = mn;
    }
    if (i < end) {
        int2 e0 = tr_sorted[i];
        float2 v = make_float2(0.f, 0.f);
        if (lane < D2) {
            float2 et = ((const float2*)(ent + (size_t)e0.x * D))[lane];
            float2 er = ((const float2*)(rel + (size_t)e0.y * D))[lane];
            v = make_float2(er.x - et.x, er.y - et.y);
        }
        float sc = edge_reduce(eh, v);
        float mn    = fmaxf(m, sc);
        float scale = __expf(m - mn);
        float ex    = __expf(sc - mn);
        den   = den * scale + ex;
        acc.x = acc.x * scale - v.x * ex;
        acc.y = acc.y * scale - v.y * ex;
        m = mn;
    }

    float inv = 1.f / (den + 1e-16f);
    float ox = acc.x * inv, oy = acc.y * inv;
    ox = ox > 0.f ? ox : expm1f(ox);           // ELU
    oy = oy > 0.f ? oy : expm1f(oy);
    if (lane < D2)
        ((float2*)(out + (size_t)head * D))[lane] = make_float2(ox, oy);
}

extern "C" void kernel_launch(void* const* d_in, const int* in_sizes, int n_in,
                              void* d_out, int out_size, void* d_ws, size_t ws_size,
                              hipStream_t stream) {
    const float* entity_emb = (const float*)d_in[0];   // [N_ENT, D]
    const float* rel_emb    = (const float*)d_in[1];   // [N_REL, D]
    const float* W          = (const float*)d_in[2];   // [D, D]
    const int*   edge_index = (const int*)d_in[3];     // [2, N_EDGE]
    const int*   edge_type  = (const int*)d_in[4];     // [N_EDGE]
    float*       out        = (float*)d_out;           // [N_ENT, D]

    const int* h_idx = edge_index;             // row 0: head/destination
    const int* t_idx = edge_index + N_EDGE;    // row 1: tail/source

    // workspace layout (~27 MB)
    float* ent       = (float*)d_ws;                    // 5,000,000 f
    float* rel       = ent + (size_t)N_ENT * D;         //    50,000 f
    int*   deg       = (int*)(rel + (size_t)N_REL * D); //    50,000 i
    int*   rowptr    = deg + N_ENT;                     //    50,001 i
    int*   cursor    = rowptr + (N_ENT + 1);            //    50,000 i
    int*   bsum      = cursor + N_ENT;                  //       256 i
    int*   boff      = bsum + SCAN_B;                   //       256 i
    int2*  tr_sorted = (int2*)(boff + SCAN_B);          //   800,000 int2

    hipMemsetAsync(deg, 0, N_ENT * sizeof(int), stream);

    // projections (entity: exact tiling, no guard; rel: guarded)
    proj_kernel<false><<<N_ENT / (2 * PROJ_RPT), 256, 0, stream>>>(
        entity_emb, W, ent, N_ENT);
    proj_kernel<true><<<(N_REL + 2 * PROJ_RPT - 1) / (2 * PROJ_RPT), 256, 0, stream>>>(
        rel_emb, W, rel, N_REL);

    // CSR build
    degree_kernel<<<(N_EDGE + 255) / 256, 256, 0, stream>>>(h_idx, deg);
    scan1_kernel<<<NBLK_SCAN, SCAN_B, 0, stream>>>(deg, bsum);
    scan2_kernel<<<1, SCAN_B, 0, stream>>>(bsum, boff);
    scan3_kernel<<<NBLK_SCAN, SCAN_B, 0, stream>>>(deg, boff, rowptr, cursor);
    fill_kernel<<<(N_EDGE + 255) / 256, 256, 0, stream>>>(h_idx, t_idx, edge_type,
                                                          cursor, tr_sorted);

    // fused score + online-softmax + message + ELU (one wave per head)
    fused_kernel<<<(N_ENT + 3) / 4, 256, 0, stream>>>(ent, rel, rowptr,
                                                      tr_sorted, out);
}

// Round 7
// 368.282 us; speedup vs baseline: 1.1683x; 1.1683x over previous
//
#include <hip/hip_runtime.h>
#include <math.h>

#define N_ENT  50000
#define N_REL  500
#define N_EDGE 800000
#define D      100
#define D2     50          // float2 lanes per row
#define ALPHA  0.2f

#define SCAN_B 256
#define NBLK_SCAN ((N_ENT + SCAN_B - 1) / SCAN_B)   // 196

// ---------------------------------------------------------------------------
// K1: Y = X @ W, W-stationary. 128 threads (2 waves), lane c<100 active.
// Each thread keeps W[:,c] in 100 VGPRs (one coalesced preload).
// X row reads are wave-uniform float4 -> scalar/broadcast loads (SGPR side),
// so unrolling does NOT blow up VGPR pressure (the R6 failure mode).
// 4 independent row accumulators = 4 FMA chains -> FMA-issue-bound.
// 20 rows/block: 50000=2500x20, 500=25x20 exact -> no guards.
// ---------------------------------------------------------------------------
#define PROJ_TPB  128
#define PROJ_ROWS 20
__global__ __launch_bounds__(PROJ_TPB) void proj_kernel(const float* __restrict__ X,
                                                        const float* __restrict__ W,
                                                        float* __restrict__ Y) {
    int c = threadIdx.x;
    if (c >= D) return;

    float w[D];
    #pragma unroll
    for (int k = 0; k < D; ++k) w[k] = W[k * D + c];   // coalesced, L1/L2-hot

    int rbase = blockIdx.x * PROJ_ROWS;
    for (int rg = 0; rg < PROJ_ROWS; rg += 4) {
        const float4* x0 = (const float4*)(X + (size_t)(rbase + rg    ) * D);
        const float4* x1 = (const float4*)(X + (size_t)(rbase + rg + 1) * D);
        const float4* x2 = (const float4*)(X + (size_t)(rbase + rg + 2) * D);
        const float4* x3 = (const float4*)(X + (size_t)(rbase + rg + 3) * D);
        float a0 = 0.f, a1 = 0.f, a2 = 0.f, a3 = 0.f;
        #pragma unroll
        for (int q = 0; q < D / 4; ++q) {
            float4 v0 = x0[q], v1 = x1[q], v2 = x2[q], v3 = x3[q];
            a0 = fmaf(v0.x, w[4*q  ], a0); a0 = fmaf(v0.y, w[4*q+1], a0);
            a0 = fmaf(v0.z, w[4*q+2], a0); a0 = fmaf(v0.w, w[4*q+3], a0);
            a1 = fmaf(v1.x, w[4*q  ], a1); a1 = fmaf(v1.y, w[4*q+1], a1);
            a1 = fmaf(v1.z, w[4*q+2], a1); a1 = fmaf(v1.w, w[4*q+3], a1);
            a2 = fmaf(v2.x, w[4*q  ], a2); a2 = fmaf(v2.y, w[4*q+1], a2);
            a2 = fmaf(v2.z, w[4*q+2], a2); a2 = fmaf(v2.w, w[4*q+3], a2);
            a3 = fmaf(v3.x, w[4*q  ], a3); a3 = fmaf(v3.y, w[4*q+1], a3);
            a3 = fmaf(v3.z, w[4*q+2], a3); a3 = fmaf(v3.w, w[4*q+3], a3);
        }
        Y[(size_t)(rbase + rg    ) * D + c] = a0;
        Y[(size_t)(rbase + rg + 1) * D + c] = a1;
        Y[(size_t)(rbase + rg + 2) * D + c] = a2;
        Y[(size_t)(rbase + rg + 3) * D + c] = a3;
    }
}

// ---------------------------------------------------------------------------
// CSR build: degree count -> block scan (3 kernels) -> fill buckets
// ---------------------------------------------------------------------------
__global__ void degree_kernel(const int* __restrict__ h_idx, int* __restrict__ deg) {
    int e = blockIdx.x * blockDim.x + threadIdx.x;
    if (e < N_EDGE) atomicAdd(&deg[h_idx[e]], 1);
}

__global__ void scan1_kernel(const int* __restrict__ deg, int* __restrict__ bsum) {
    __shared__ int s[SCAN_B];
    int i = blockIdx.x * SCAN_B + threadIdx.x;
    s[threadIdx.x] = (i < N_ENT) ? deg[i] : 0;
    __syncthreads();
    for (int off = SCAN_B / 2; off; off >>= 1) {
        if (threadIdx.x < off) s[threadIdx.x] += s[threadIdx.x + off];
        __syncthreads();
    }
    if (threadIdx.x == 0) bsum[blockIdx.x] = s[0];
}

__global__ void scan2_kernel(const int* __restrict__ bsum, int* __restrict__ boff) {
    __shared__ int s[SCAN_B];
    int tid = threadIdx.x;
    int v = (tid < NBLK_SCAN) ? bsum[tid] : 0;
    s[tid] = v;
    __syncthreads();
    for (int off = 1; off < SCAN_B; off <<= 1) {
        int x = (tid >= off) ? s[tid - off] : 0;
        __syncthreads();
        s[tid] += x;
        __syncthreads();
    }
    if (tid < NBLK_SCAN) boff[tid] = s[tid] - v;   // exclusive
}

__global__ void scan3_kernel(const int* __restrict__ deg, const int* __restrict__ boff,
                             int* __restrict__ rowptr, int* __restrict__ cursor) {
    __shared__ int s[SCAN_B];
    int tid = threadIdx.x;
    int i = blockIdx.x * SCAN_B + tid;
    int v = (i < N_ENT) ? deg[i] : 0;
    s[tid] = v;
    __syncthreads();
    for (int off = 1; off < SCAN_B; off <<= 1) {
        int x = (tid >= off) ? s[tid - off] : 0;
        __syncthreads();
        s[tid] += x;
        __syncthreads();
    }
    int excl = s[tid] - v + boff[blockIdx.x];
    if (i < N_ENT) { rowptr[i] = excl; cursor[i] = excl; }
    if (i == N_ENT - 1) rowptr[N_ENT] = excl + v;
}

__global__ void fill_kernel(const int* __restrict__ h_idx, const int* __restrict__ t_idx,
                            const int* __restrict__ etype, int* __restrict__ cursor,
                            int2* __restrict__ tr_sorted) {
    int e = blockIdx.x * blockDim.x + threadIdx.x;
    if (e >= N_EDGE) return;
    int h = h_idx[e];
    int pos = atomicAdd(&cursor[h], 1);
    tr_sorted[pos] = make_int2(t_idx[e], etype[e]);
}

// ---------------------------------------------------------------------------
// Fused per-head kernel: one 64-lane wave per head node, online softmax,
// unroll-by-2 so the two edges' gathers issue before either serial chain.
// ---------------------------------------------------------------------------
__device__ __forceinline__ float edge_reduce(float2 eh, float2 v) {
    float dx = eh.x + v.x, dy = eh.y + v.y;
    float s = fmaf(dx, dx, dy * dy);
    #pragma unroll
    for (int off = 32; off; off >>= 1) s += __shfl_xor(s, off, 64);
    return sqrtf(s);                       // leaky_relu identity (s >= 0)
}

__global__ void fused_kernel(const float* __restrict__ ent, const float* __restrict__ rel,
                             const int* __restrict__ rowptr,
                             const int2* __restrict__ tr_sorted,
                             float* __restrict__ out) {
    int head = blockIdx.x * 4 + (threadIdx.x >> 6);
    int lane = threadIdx.x & 63;
    if (head >= N_ENT) return;
    int beg = rowptr[head], end = rowptr[head + 1];

    float2 eh = make_float2(0.f, 0.f);
    if (lane < D2) eh = ((const float2*)(ent + (size_t)head * D))[lane];

    float  m   = -INFINITY;
    float  den = 0.f;
    float2 acc = make_float2(0.f, 0.f);

    int i = beg;
    for (; i + 1 < end; i += 2) {
        int2 e0 = tr_sorted[i];
        int2 e1 = tr_sorted[i + 1];
        float2 v0 = make_float2(0.f, 0.f), v1 = make_float2(0.f, 0.f);
        if (lane < D2) {
            float2 et0 = ((const float2*)(ent + (size_t)e0.x * D))[lane];
            float2 er0 = ((const float2*)(rel + (size_t)e0.y * D))[lane];
            float2 et1 = ((const float2*)(ent + (size_t)e1.x * D))[lane];
            float2 er1 = ((const float2*)(rel + (size_t)e1.y * D))[lane];
            v0 = make_float2(er0.x - et0.x, er0.y - et0.y);
            v1 = make_float2(er1.x - et1.x, er1.y - et1.y);
        }
        float sc0 = edge_reduce(eh, v0);
        float sc1 = edge_reduce(eh, v1);

        float mn    = fmaxf(m, sc0);
        float scale = __expf(m - mn);
        float ex    = __expf(sc0 - mn);
        den   = den * scale + ex;
        acc.x = acc.x * scale - v0.x * ex;
        acc.y = acc.y * scale - v0.y * ex;
        m = mn;

        mn    = fmaxf(m, sc1);
        scale = __expf(m - mn);
        ex    = __expf(sc1 - mn);
        den   = den * scale + ex;
        acc.x = acc.x * scale - v1.x * ex;
        acc.y = acc.y * scale - v1.y * ex;
        m = mn;
    }
    if (i < end) {
        int2 e0 = tr_sorted[i];
        float2 v = make_float2(0.f, 0.f);
        if (lane < D2) {
            float2 et = ((const float2*)(ent + (size_t)e0.x * D))[lane];
            float2 er = ((const float2*)(rel + (size_t)e0.y * D))[lane];
            v = make_float2(er.x - et.x, er.y - et.y);
        }
        float sc = edge_reduce(eh, v);
        float mn    = fmaxf(m, sc);
        float scale = __expf(m - mn);
        float ex    = __expf(sc - mn);
        den   = den * scale + ex;
        acc.x = acc.x * scale - v.x * ex;
        acc.y = acc.y * scale - v.y * ex;
        m = mn;
    }

    float inv = 1.f / (den + 1e-16f);
    float ox = acc.x * inv, oy = acc.y * inv;
    ox = ox > 0.f ? ox : expm1f(ox);           // ELU
    oy = oy > 0.f ? oy : expm1f(oy);
    if (lane < D2)
        ((float2*)(out + (size_t)head * D))[lane] = make_float2(ox, oy);
}

extern "C" void kernel_launch(void* const* d_in, const int* in_sizes, int n_in,
                              void* d_out, int out_size, void* d_ws, size_t ws_size,
                              hipStream_t stream) {
    const float* entity_emb = (const float*)d_in[0];   // [N_ENT, D]
    const float* rel_emb    = (const float*)d_in[1];   // [N_REL, D]
    const float* W          = (const float*)d_in[2];   // [D, D]
    const int*   edge_index = (const int*)d_in[3];     // [2, N_EDGE]
    const int*   edge_type  = (const int*)d_in[4];     // [N_EDGE]
    float*       out        = (float*)d_out;           // [N_ENT, D]

    const int* h_idx = edge_index;             // row 0: head/destination
    const int* t_idx = edge_index + N_EDGE;    // row 1: tail/source

    // workspace layout (~27 MB)
    float* ent       = (float*)d_ws;                    // 5,000,000 f
    float* rel       = ent + (size_t)N_ENT * D;         //    50,000 f
    int*   deg       = (int*)(rel + (size_t)N_REL * D); //    50,000 i
    int*   rowptr    = deg + N_ENT;                     //    50,001 i
    int*   cursor    = rowptr + (N_ENT + 1);            //    50,000 i
    int*   bsum      = cursor + N_ENT;                  //       256 i
    int*   boff      = bsum + SCAN_B;                   //       256 i
    int2*  tr_sorted = (int2*)(boff + SCAN_B);          //   800,000 int2

    hipMemsetAsync(deg, 0, N_ENT * sizeof(int), stream);

    // projections: W-stationary, exact tilings (50000=2500*20, 500=25*20)
    proj_kernel<<<N_ENT / PROJ_ROWS, PROJ_TPB, 0, stream>>>(entity_emb, W, ent);
    proj_kernel<<<N_REL / PROJ_ROWS, PROJ_TPB, 0, stream>>>(rel_emb, W, rel);

    // CSR build
    degree_kernel<<<(N_EDGE + 255) / 256, 256, 0, stream>>>(h_idx, deg);
    scan1_kernel<<<NBLK_SCAN, SCAN_B, 0, stream>>>(deg, bsum);
    scan2_kernel<<<1, SCAN_B, 0, stream>>>(bsum, boff);
    scan3_kernel<<<NBLK_SCAN, SCAN_B, 0, stream>>>(deg, boff, rowptr, cursor);
    fill_kernel<<<(N_EDGE + 255) / 256, 256, 0, stream>>>(h_idx, t_idx, edge_type,
                                                          cursor, tr_sorted);

    // fused score + online-softmax + message + ELU (one wave per head)
    fused_kernel<<<(N_ENT + 3) / 4, 256, 0, stream>>>(ent, rel, rowptr,
                                                      tr_sorted, out);
}

// Round 8
// 298.241 us; speedup vs baseline: 1.4427x; 1.2348x over previous
//
#include <hip/hip_runtime.h>
#include <math.h>

#define N_ENT  50000
#define N_REL  500
#define N_EDGE 800000
#define D      100
#define D2     50          // float2 lanes per row
#define ALPHA  0.2f

#define SCAN_B 256
#define NBLK_SCAN ((N_ENT + SCAN_B - 1) / SCAN_B)   // 196

// ---------------------------------------------------------------------------
// K1: Y = X @ W. W^T staged in LDS at stride 101 (gcd(101%32=5,32)=1 ->
// lane c reads WT[c*101+k]: bank permutation, conflict-free). X tile (50
// rows) in LDS; X reads are wave-uniform -> broadcast. 256 threads, 200
// active in compute: thread = (c = t%100, rg = t/100), 25 rows each, 5 rows
// per k-pass so one W-read feeds 5 FMAs. 50000=1000*50, 500=10*50 exact.
// ---------------------------------------------------------------------------
#define PROJ_TPB  256
#define PROJ_RPB  50      // rows per block
#define PROJ_RPT  25      // rows per thread (one rg half)
#define WT_STRIDE 101

__global__ __launch_bounds__(PROJ_TPB) void proj_kernel(const float* __restrict__ X,
                                                        const float* __restrict__ W,
                                                        float* __restrict__ Y) {
    __shared__ float WT[D * WT_STRIDE];   // 40.4 KB
    __shared__ float Xs[PROJ_RPB * D];    // 20 KB
    int t = threadIdx.x;

    // W^T load: i = k*100+c consecutive -> coalesced global read;
    // LDS write addr c*101+k -> stride 101 across lanes -> conflict-free.
    for (int i = t; i < D * D; i += PROJ_TPB) {
        int k = i / D, c = i % D;
        WT[c * WT_STRIDE + k] = W[i];
    }
    size_t xbase = (size_t)blockIdx.x * PROJ_RPB * D;
    for (int i = t; i < PROJ_RPB * D; i += PROJ_TPB)
        Xs[i] = X[xbase + i];
    __syncthreads();

    if (t < 200) {
        int c  = t % 100;
        int r0 = (t / 100) * PROJ_RPT;    // local row base for this half
        const float* wt = &WT[c * WT_STRIDE];
        for (int j = 0; j < PROJ_RPT; j += 5) {
            const float* x0 = &Xs[(r0 + j    ) * D];
            const float* x1 = &Xs[(r0 + j + 1) * D];
            const float* x2 = &Xs[(r0 + j + 2) * D];
            const float* x3 = &Xs[(r0 + j + 3) * D];
            const float* x4 = &Xs[(r0 + j + 4) * D];
            float a0 = 0.f, a1 = 0.f, a2 = 0.f, a3 = 0.f, a4 = 0.f;
            #pragma unroll
            for (int k = 0; k < D; ++k) {
                float w = wt[k];
                a0 = fmaf(x0[k], w, a0);
                a1 = fmaf(x1[k], w, a1);
                a2 = fmaf(x2[k], w, a2);
                a3 = fmaf(x3[k], w, a3);
                a4 = fmaf(x4[k], w, a4);
            }
            Y[xbase + (size_t)(r0 + j    ) * D + c] = a0;
            Y[xbase + (size_t)(r0 + j + 1) * D + c] = a1;
            Y[xbase + (size_t)(r0 + j + 2) * D + c] = a2;
            Y[xbase + (size_t)(r0 + j + 3) * D + c] = a3;
            Y[xbase + (size_t)(r0 + j + 4) * D + c] = a4;
        }
    }
}

// ---------------------------------------------------------------------------
// CSR build: degree count -> block scan (3 kernels) -> fill buckets
// ---------------------------------------------------------------------------
__global__ void degree_kernel(const int* __restrict__ h_idx, int* __restrict__ deg) {
    int e = blockIdx.x * blockDim.x + threadIdx.x;
    if (e < N_EDGE) atomicAdd(&deg[h_idx[e]], 1);
}

__global__ void scan1_kernel(const int* __restrict__ deg, int* __restrict__ bsum) {
    __shared__ int s[SCAN_B];
    int i = blockIdx.x * SCAN_B + threadIdx.x;
    s[threadIdx.x] = (i < N_ENT) ? deg[i] : 0;
    __syncthreads();
    for (int off = SCAN_B / 2; off; off >>= 1) {
        if (threadIdx.x < off) s[threadIdx.x] += s[threadIdx.x + off];
        __syncthreads();
    }
    if (threadIdx.x == 0) bsum[blockIdx.x] = s[0];
}

__global__ void scan2_kernel(const int* __restrict__ bsum, int* __restrict__ boff) {
    __shared__ int s[SCAN_B];
    int tid = threadIdx.x;
    int v = (tid < NBLK_SCAN) ? bsum[tid] : 0;
    s[tid] = v;
    __syncthreads();
    for (int off = 1; off < SCAN_B; off <<= 1) {
        int x = (tid >= off) ? s[tid - off] : 0;
        __syncthreads();
        s[tid] += x;
        __syncthreads();
    }
    if (tid < NBLK_SCAN) boff[tid] = s[tid] - v;   // exclusive
}

__global__ void scan3_kernel(const int* __restrict__ deg, const int* __restrict__ boff,
                             int* __restrict__ rowptr, int* __restrict__ cursor) {
    __shared__ int s[SCAN_B];
    int tid = threadIdx.x;
    int i = blockIdx.x * SCAN_B + tid;
    int v = (i < N_ENT) ? deg[i] : 0;
    s[tid] = v;
    __syncthreads();
    for (int off = 1; off < SCAN_B; off <<= 1) {
        int x = (tid >= off) ? s[tid - off] : 0;
        __syncthreads();
        s[tid] += x;
        __syncthreads();
    }
    int excl = s[tid] - v + boff[blockIdx.x];
    if (i < N_ENT) { rowptr[i] = excl; cursor[i] = excl; }
    if (i == N_ENT - 1) rowptr[N_ENT] = excl + v;
}

__global__ void fill_kernel(const int* __restrict__ h_idx, const int* __restrict__ t_idx,
                            const int* __restrict__ etype, int* __restrict__ cursor,
                            int2* __restrict__ tr_sorted) {
    int e = blockIdx.x * blockDim.x + threadIdx.x;
    if (e >= N_EDGE) return;
    int h = h_idx[e];
    int pos = atomicAdd(&cursor[h], 1);
    tr_sorted[pos] = make_int2(t_idx[e], etype[e]);
}

// ---------------------------------------------------------------------------
// Fused per-head kernel: one 64-lane wave per head node, online softmax,
// unroll-by-2 so the two edges' gathers issue before either serial chain.
// ---------------------------------------------------------------------------
__device__ __forceinline__ float edge_reduce(float2 eh, float2 v) {
    float dx = eh.x + v.x, dy = eh.y + v.y;
    float s = fmaf(dx, dx, dy * dy);
    #pragma unroll
    for (int off = 32; off; off >>= 1) s += __shfl_xor(s, off, 64);
    return sqrtf(s);                       // leaky_relu identity (s >= 0)
}

__global__ void fused_kernel(const float* __restrict__ ent, const float* __restrict__ rel,
                             const int* __restrict__ rowptr,
                             const int2* __restrict__ tr_sorted,
                             float* __restrict__ out) {
    int head = blockIdx.x * 4 + (threadIdx.x >> 6);
    int lane = threadIdx.x & 63;
    if (head >= N_ENT) return;
    int beg = rowptr[head], end = rowptr[head + 1];

    float2 eh = make_float2(0.f, 0.f);
    if (lane < D2) eh = ((const float2*)(ent + (size_t)head * D))[lane];

    float  m   = -INFINITY;
    float  den = 0.f;
    float2 acc = make_float2(0.f, 0.f);

    int i = beg;
    for (; i + 1 < end; i += 2) {
        int2 e0 = tr_sorted[i];
        int2 e1 = tr_sorted[i + 1];
        float2 v0 = make_float2(0.f, 0.f), v1 = make_float2(0.f, 0.f);
        if (lane < D2) {
            float2 et0 = ((const float2*)(ent + (size_t)e0.x * D))[lane];
            float2 er0 = ((const float2*)(rel + (size_t)e0.y * D))[lane];
            float2 et1 = ((const float2*)(ent + (size_t)e1.x * D))[lane];
            float2 er1 = ((const float2*)(rel + (size_t)e1.y * D))[lane];
            v0 = make_float2(er0.x - et0.x, er0.y - et0.y);
            v1 = make_float2(er1.x - et1.x, er1.y - et1.y);
        }
        float sc0 = edge_reduce(eh, v0);
        float sc1 = edge_reduce(eh, v1);

        float mn    = fmaxf(m, sc0);
        float scale = __expf(m - mn);
        float ex    = __expf(sc0 - mn);
        den   = den * scale + ex;
        acc.x = acc.x * scale - v0.x * ex;
        acc.y = acc.y * scale - v0.y * ex;
        m = mn;

        mn    = fmaxf(m, sc1);
        scale = __expf(m - mn);
        ex    = __expf(sc1 - mn);
        den   = den * scale + ex;
        acc.x = acc.x * scale - v1.x * ex;
        acc.y = acc.y * scale - v1.y * ex;
        m = mn;
    }
    if (i < end) {
        int2 e0 = tr_sorted[i];
        float2 v = make_float2(0.f, 0.f);
        if (lane < D2) {
            float2 et = ((const float2*)(ent + (size_t)e0.x * D))[lane];
            float2 er = ((const float2*)(rel + (size_t)e0.y * D))[lane];
            v = make_float2(er.x - et.x, er.y - et.y);
        }
        float sc = edge_reduce(eh, v);
        float mn    = fmaxf(m, sc);
        float scale = __expf(m - mn);
        float ex    = __expf(sc - mn);
        den   = den * scale + ex;
        acc.x = acc.x * scale - v.x * ex;
        acc.y = acc.y * scale - v.y * ex;
        m = mn;
    }

    float inv = 1.f / (den + 1e-16f);
    float ox = acc.x * inv, oy = acc.y * inv;
    ox = ox > 0.f ? ox : expm1f(ox);           // ELU
    oy = oy > 0.f ? oy : expm1f(oy);
    if (lane < D2)
        ((float2*)(out + (size_t)head * D))[lane] = make_float2(ox, oy);
}

extern "C" void kernel_launch(void* const* d_in, const int* in_sizes, int n_in,
                              void* d_out, int out_size, void* d_ws, size_t ws_size,
                              hipStream_t stream) {
    const float* entity_emb = (const float*)d_in[0];   // [N_ENT, D]
    const float* rel_emb    = (const float*)d_in[1];   // [N_REL, D]
    const float* W          = (const float*)d_in[2];   // [D, D]
    const int*   edge_index = (const int*)d_in[3];     // [2, N_EDGE]
    const int*   edge_type  = (const int*)d_in[4];     // [N_EDGE]
    float*       out        = (float*)d_out;           // [N_ENT, D]

    const int* h_idx = edge_index;             // row 0: head/destination
    const int* t_idx = edge_index + N_EDGE;    // row 1: tail/source

    // workspace layout (~27 MB)
    float* ent       = (float*)d_ws;                    // 5,000,000 f
    float* rel       = ent + (size_t)N_ENT * D;         //    50,000 f
    int*   deg       = (int*)(rel + (size_t)N_REL * D); //    50,000 i
    int*   rowptr    = deg + N_ENT;                     //    50,001 i
    int*   cursor    = rowptr + (N_ENT + 1);            //    50,000 i
    int*   bsum      = cursor + N_ENT;                  //       256 i
    int*   boff      = bsum + SCAN_B;                   //       256 i
    int2*  tr_sorted = (int2*)(boff + SCAN_B);          //   800,000 int2

    hipMemsetAsync(deg, 0, N_ENT * sizeof(int), stream);

    // projections: LDS-staged W^T (stride 101) + X tile; exact tilings
    proj_kernel<<<N_ENT / PROJ_RPB, PROJ_TPB, 0, stream>>>(entity_emb, W, ent);
    proj_kernel<<<N_REL / PROJ_RPB, PROJ_TPB, 0, stream>>>(rel_emb, W, rel);

    // CSR build
    degree_kernel<<<(N_EDGE + 255) / 256, 256, 0, stream>>>(h_idx, deg);
    scan1_kernel<<<NBLK_SCAN, SCAN_B, 0, stream>>>(deg, bsum);
    scan2_kernel<<<1, SCAN_B, 0, stream>>>(bsum, boff);
    scan3_kernel<<<NBLK_SCAN, SCAN_B, 0, stream>>>(deg, boff, rowptr, cursor);
    fill_kernel<<<(N_EDGE + 255) / 256, 256, 0, stream>>>(h_idx, t_idx, edge_type,
                                                          cursor, tr_sorted);

    // fused score + online-softmax + message + ELU (one wave per head)
    fused_kernel<<<(N_ENT + 3) / 4, 256, 0, stream>>>(ent, rel, rowptr,
                                                      tr_sorted, out);
}

// Round 10
// 273.824 us; speedup vs baseline: 1.5714x; 1.0892x over previous
//
#include <hip/hip_runtime.h>
#include <math.h>

#define N_ENT  50000
#define N_REL  500
#define N_EDGE 800000
#define D      100
#define ALPHA  0.2f

#define SCAN_B 256
#define NBLK_SCAN ((N_ENT + SCAN_B - 1) / SCAN_B)   // 196

// ---------------------------------------------------------------------------
// K1: Y = X @ W. W^T staged in LDS at stride 101 (conflict-free); X tile in
// LDS (broadcast reads). 50 rows/block. (unchanged from R8 — proved good)
// ---------------------------------------------------------------------------
#define PROJ_TPB  256
#define PROJ_RPB  50
#define PROJ_RPT  25
#define WT_STRIDE 101

__global__ __launch_bounds__(PROJ_TPB) void proj_kernel(const float* __restrict__ X,
                                                        const float* __restrict__ W,
                                                        float* __restrict__ Y) {
    __shared__ float WT[D * WT_STRIDE];   // 40.4 KB
    __shared__ float Xs[PROJ_RPB * D];    // 20 KB
    int t = threadIdx.x;

    for (int i = t; i < D * D; i += PROJ_TPB) {
        int k = i / D, c = i % D;
        WT[c * WT_STRIDE + k] = W[i];
    }
    size_t xbase = (size_t)blockIdx.x * PROJ_RPB * D;
    for (int i = t; i < PROJ_RPB * D; i += PROJ_TPB)
        Xs[i] = X[xbase + i];
    __syncthreads();

    if (t < 200) {
        int c  = t % 100;
        int r0 = (t / 100) * PROJ_RPT;
        const float* wt = &WT[c * WT_STRIDE];
        for (int j = 0; j < PROJ_RPT; j += 5) {
            const float* x0 = &Xs[(r0 + j    ) * D];
            const float* x1 = &Xs[(r0 + j + 1) * D];
            const float* x2 = &Xs[(r0 + j + 2) * D];
            const float* x3 = &Xs[(r0 + j + 3) * D];
            const float* x4 = &Xs[(r0 + j + 4) * D];
            float a0 = 0.f, a1 = 0.f, a2 = 0.f, a3 = 0.f, a4 = 0.f;
            #pragma unroll
            for (int k = 0; k < D; ++k) {
                float w = wt[k];
                a0 = fmaf(x0[k], w, a0);
                a1 = fmaf(x1[k], w, a1);
                a2 = fmaf(x2[k], w, a2);
                a3 = fmaf(x3[k], w, a3);
                a4 = fmaf(x4[k], w, a4);
            }
            Y[xbase + (size_t)(r0 + j    ) * D + c] = a0;
            Y[xbase + (size_t)(r0 + j + 1) * D + c] = a1;
            Y[xbase + (size_t)(r0 + j + 2) * D + c] = a2;
            Y[xbase + (size_t)(r0 + j + 3) * D + c] = a3;
            Y[xbase + (size_t)(r0 + j + 4) * D + c] = a4;
        }
    }
}

// ---------------------------------------------------------------------------
// CSR build: degree count -> block scan (3 kernels) -> fill buckets
// ---------------------------------------------------------------------------
__global__ void degree_kernel(const int* __restrict__ h_idx, int* __restrict__ deg) {
    int e = blockIdx.x * blockDim.x + threadIdx.x;
    if (e < N_EDGE) atomicAdd(&deg[h_idx[e]], 1);
}

__global__ void scan1_kernel(const int* __restrict__ deg, int* __restrict__ bsum) {
    __shared__ int s[SCAN_B];
    int i = blockIdx.x * SCAN_B + threadIdx.x;
    s[threadIdx.x] = (i < N_ENT) ? deg[i] : 0;
    __syncthreads();
    for (int off = SCAN_B / 2; off; off >>= 1) {
        if (threadIdx.x < off) s[threadIdx.x] += s[threadIdx.x + off];
        __syncthreads();
    }
    if (threadIdx.x == 0) bsum[blockIdx.x] = s[0];
}

__global__ void scan2_kernel(const int* __restrict__ bsum, int* __restrict__ boff) {
    __shared__ int s[SCAN_B];
    int tid = threadIdx.x;
    int v = (tid < NBLK_SCAN) ? bsum[tid] : 0;
    s[tid] = v;
    __syncthreads();
    for (int off = 1; off < SCAN_B; off <<= 1) {
        int x = (tid >= off) ? s[tid - off] : 0;
        __syncthreads();
        s[tid] += x;
        __syncthreads();
    }
    if (tid < NBLK_SCAN) boff[tid] = s[tid] - v;   // exclusive
}

__global__ void scan3_kernel(const int* __restrict__ deg, const int* __restrict__ boff,
                             int* __restrict__ rowptr, int* __restrict__ cursor) {
    __shared__ int s[SCAN_B];
    int tid = threadIdx.x;
    int i = blockIdx.x * SCAN_B + tid;
    int v = (i < N_ENT) ? deg[i] : 0;
    s[tid] = v;
    __syncthreads();
    for (int off = 1; off < SCAN_B; off <<= 1) {
        int x = (tid >= off) ? s[tid - off] : 0;
        __syncthreads();
        s[tid] += x;
        __syncthreads();
    }
    int excl = s[tid] - v + boff[blockIdx.x];
    if (i < N_ENT) { rowptr[i] = excl; cursor[i] = excl; }
    if (i == N_ENT - 1) rowptr[N_ENT] = excl + v;
}

__global__ void fill_kernel(const int* __restrict__ h_idx, const int* __restrict__ t_idx,
                            const int* __restrict__ etype, int* __restrict__ cursor,
                            int2* __restrict__ tr_sorted) {
    int e = blockIdx.x * blockDim.x + threadIdx.x;
    if (e >= N_EDGE) return;
    int h = h_idx[e];
    int pos = atomicAdd(&cursor[h], 1);
    tr_sorted[pos] = make_int2(t_idx[e], etype[e]);
}

// ---------------------------------------------------------------------------
// Fused kernel: ONE HEAD PER 32-LANE HALF-WAVE, float4 per lane (25 active
// lanes hold the 100-dim row). Every wave instruction serves 2 edges (one
// per half); reduce is 5 stages at width 32. Half-wave loop divergence is
// handled by the exec mask (per-half control is uniform). Online softmax.
// ---------------------------------------------------------------------------
__device__ __forceinline__ float edge_reduce32(const float4& eh, const float4& v) {
    float dx = eh.x + v.x, dy = eh.y + v.y, dz = eh.z + v.z, dw = eh.w + v.w;
    float s = dx * dx;
    s = fmaf(dy, dy, s);
    s = fmaf(dz, dz, s);
    s = fmaf(dw, dw, s);
    #pragma unroll
    for (int off = 16; off; off >>= 1) s += __shfl_xor(s, off, 32);
    return sqrtf(s);                       // leaky_relu identity (s >= 0)
}

__global__ __launch_bounds__(256) void fused_kernel(const float* __restrict__ ent,
                                                    const float* __restrict__ rel,
                                                    const int* __restrict__ rowptr,
                                                    const int2* __restrict__ tr_sorted,
                                                    float* __restrict__ out) {
    int head = blockIdx.x * 8 + (threadIdx.x >> 5);   // 8 half-waves per block
    int lane = threadIdx.x & 31;                      // lane within half-wave
    if (head >= N_ENT) return;                        // grid exact: 6250*8
    int beg = rowptr[head], end = rowptr[head + 1];

    float4 eh = make_float4(0.f, 0.f, 0.f, 0.f);
    if (lane < 25) eh = ((const float4*)(ent + (size_t)head * D))[lane];

    float  m   = -INFINITY;
    float  den = 0.f;
    float4 acc = make_float4(0.f, 0.f, 0.f, 0.f);

    int i = beg;
    for (; i + 1 < end; i += 2) {
        int2 e0 = tr_sorted[i];
        int2 e1 = tr_sorted[i + 1];
        float4 v0 = make_float4(0.f, 0.f, 0.f, 0.f);
        float4 v1 = make_float4(0.f, 0.f, 0.f, 0.f);
        if (lane < 25) {
            float4 et0 = ((const float4*)(ent + (size_t)e0.x * D))[lane];
            float4 er0 = ((const float4*)(rel + (size_t)e0.y * D))[lane];
            float4 et1 = ((const float4*)(ent + (size_t)e1.x * D))[lane];
            float4 er1 = ((const float4*)(rel + (size_t)e1.y * D))[lane];
            v0 = make_float4(er0.x - et0.x, er0.y - et0.y, er0.z - et0.z, er0.w - et0.w);
            v1 = make_float4(er1.x - et1.x, er1.y - et1.y, er1.z - et1.z, er1.w - et1.w);
        }
        float sc0 = edge_reduce32(eh, v0);
        float sc1 = edge_reduce32(eh, v1);

        float mn    = fmaxf(m, sc0);
        float scale = __expf(m - mn);
        float ex    = __expf(sc0 - mn);
        den   = den * scale + ex;
        acc.x = acc.x * scale - v0.x * ex;
        acc.y = acc.y * scale - v0.y * ex;
        acc.z = acc.z * scale - v0.z * ex;
        acc.w = acc.w * scale - v0.w * ex;
        m = mn;

        mn    = fmaxf(m, sc1);
        scale = __expf(m - mn);
        ex    = __expf(sc1 - mn);
        den   = den * scale + ex;
        acc.x = acc.x * scale - v1.x * ex;
        acc.y = acc.y * scale - v1.y * ex;
        acc.z = acc.z * scale - v1.z * ex;
        acc.w = acc.w * scale - v1.w * ex;
        m = mn;
    }
    if (i < end) {
        int2 e0 = tr_sorted[i];
        float4 v = make_float4(0.f, 0.f, 0.f, 0.f);
        if (lane < 25) {
            float4 et = ((const float4*)(ent + (size_t)e0.x * D))[lane];
            float4 er = ((const float4*)(rel + (size_t)e0.y * D))[lane];
            v = make_float4(er.x - et.x, er.y - et.y, er.z - et.z, er.w - et.w);
        }
        float sc = edge_reduce32(eh, v);
        float mn    = fmaxf(m, sc);
        float scale = __expf(m - mn);
        float ex    = __expf(sc - mn);
        den   = den * scale + ex;
        acc.x = acc.x * scale - v.x * ex;
        acc.y = acc.y * scale - v.y * ex;
        acc.z = acc.z * scale - v.z * ex;
        acc.w = acc.w * scale - v.w * ex;
        m = mn;
    }

    float inv = 1.f / (den + 1e-16f);
    float ox = acc.x * inv, oy = acc.y * inv, oz = acc.z * inv, ow = acc.w * inv;
    ox = ox > 0.f ? ox : expm1f(ox);           // ELU
    oy = oy > 0.f ? oy : expm1f(oy);
    oz = oz > 0.f ? oz : expm1f(oz);
    ow = ow > 0.f ? ow : expm1f(ow);
    if (lane < 25)
        ((float4*)(out + (size_t)head * D))[lane] = make_float4(ox, oy, oz, ow);
}

extern "C" void kernel_launch(void* const* d_in, const int* in_sizes, int n_in,
                              void* d_out, int out_size, void* d_ws, size_t ws_size,
                              hipStream_t stream) {
    const float* entity_emb = (const float*)d_in[0];   // [N_ENT, D]
    const float* rel_emb    = (const float*)d_in[1];   // [N_REL, D]
    const float* W          = (const float*)d_in[2];   // [D, D]
    const int*   edge_index = (const int*)d_in[3];     // [2, N_EDGE]
    const int*   edge_type  = (const int*)d_in[4];     // [N_EDGE]
    float*       out        = (float*)d_out;           // [N_ENT, D]

    const int* h_idx = edge_index;             // row 0: head/destination
    const int* t_idx = edge_index + N_EDGE;    // row 1: tail/source

    // workspace layout (~27 MB)
    float* ent       = (float*)d_ws;                    // 5,000,000 f
    float* rel       = ent + (size_t)N_ENT * D;         //    50,000 f
    int*   deg       = (int*)(rel + (size_t)N_REL * D); //    50,000 i
    int*   rowptr    = deg + N_ENT;                     //    50,001 i
    int*   cursor    = rowptr + (N_ENT + 1);            //    50,000 i
    int*   bsum      = cursor + N_ENT;                  //       256 i
    int*   boff      = bsum + SCAN_B;                   //       256 i
    int2*  tr_sorted = (int2*)(boff + SCAN_B);          //   800,000 int2

    hipMemsetAsync(deg, 0, N_ENT * sizeof(int), stream);

    // projections: LDS-staged W^T (stride 101) + X tile; exact tilings
    proj_kernel<<<N_ENT / PROJ_RPB, PROJ_TPB, 0, stream>>>(entity_emb, W, ent);
    proj_kernel<<<N_REL / PROJ_RPB, PROJ_TPB, 0, stream>>>(rel_emb, W, rel);

    // CSR build
    degree_kernel<<<(N_EDGE + 255) / 256, 256, 0, stream>>>(h_idx, deg);
    scan1_kernel<<<NBLK_SCAN, SCAN_B, 0, stream>>>(deg, bsum);
    scan2_kernel<<<1, SCAN_B, 0, stream>>>(bsum, boff);
    scan3_kernel<<<NBLK_SCAN, SCAN_B, 0, stream>>>(deg, boff, rowptr, cursor);
    fill_kernel<<<(N_EDGE + 255) / 256, 256, 0, stream>>>(h_idx, t_idx, edge_type,
                                                          cursor, tr_sorted);

    // fused: one head per 32-lane half-wave (8 heads / 256-thread block)
    fused_kernel<<<N_ENT / 8, 256, 0, stream>>>(ent, rel, rowptr, tr_sorted, out);
}